// Round 7
// baseline (691.839 us; speedup 1.0000x reference)
//
#include <hip/hip_runtime.h>
#include <stdint.h>
#include <stddef.h>

// Problem constants: B=8, N=4096, D=1024
#define D_ 1024
#define NSEQ_ 4096
#define BATCH_ 8
#define BN_ (BATCH_ * NSEQ_)

typedef __attribute__((ext_vector_type(8))) short short8;
typedef __attribute__((ext_vector_type(4))) short short4_t;
typedef __attribute__((ext_vector_type(4))) float float4_t;

__device__ __forceinline__ short f2b(float f) {  // fp32 -> bf16 bits, RNE
  union { float f; uint32_t u; } x; x.f = f;
  uint32_t r = x.u + 0x7fffu + ((x.u >> 16) & 1u);
  return (short)(r >> 16);
}
__device__ __forceinline__ float b2f(short s) {
  union { float f; uint32_t u; } x; x.u = ((uint32_t)(uint16_t)s) << 16; return x.f;
}

// async global->LDS, 16B per lane; LDS dest is wave-uniform base + lane*16
__device__ __forceinline__ void gll16(const void* g, void* l) {
  auto gp = reinterpret_cast<const uint32_t __attribute__((address_space(1)))*>(
      reinterpret_cast<uintptr_t>(g));
  auto lp = reinterpret_cast<uint32_t __attribute__((address_space(3)))*>(
      reinterpret_cast<uintptr_t>(l));
  __builtin_amdgcn_global_load_lds(gp, lp, 16, 0, 0);
}

#define MFMA16(a, b, c) __builtin_amdgcn_mfma_f32_16x16x32_bf16(a, b, c, 0, 0, 0)

// ---------------------------------------------------------------------------
// Kernel A: x fp32 -> bf16 (memory-bound). X read once -> non-temporal loads.
// ---------------------------------------------------------------------------
__global__ void convert_x(const float* __restrict__ X, short* __restrict__ Xb) {
  const size_t i = (size_t)blockIdx.x * 256 + threadIdx.x;  // 8 elems each
  const float4_t* p = (const float4_t*)(X + i * 8);
  float4_t a = __builtin_nontemporal_load(p);
  float4_t b = __builtin_nontemporal_load(p + 1);
  short8 o;
  o[0] = f2b(a.x); o[1] = f2b(a.y); o[2] = f2b(a.z); o[3] = f2b(a.w);
  o[4] = f2b(b.x); o[5] = f2b(b.y); o[6] = f2b(b.z); o[7] = f2b(b.w);
  *(short8*)(Xb + i * 8) = o;
}

// ---------------------------------------------------------------------------
// Kernel 0: weights (D,D) fp32 -> transposed bf16, INTERLEAVED layout:
//   Wint[(e>>4)*64 + z*16 + (e&15)][d] = W_z[d][e]
// ---------------------------------------------------------------------------
__global__ void transpose_convert_w(const float* __restrict__ w0, const float* __restrict__ w1,
                                    const float* __restrict__ w2, const float* __restrict__ w3,
                                    short* __restrict__ wT) {
  __shared__ float tile[32][33];
  const int z = blockIdx.z;
  const float* src = (z == 0) ? w0 : (z == 1) ? w1 : (z == 2) ? w2 : w3;
  const int d0 = blockIdx.y * 32, e0 = blockIdx.x * 32;
  const int tx = threadIdx.x, ty = threadIdx.y;
#pragma unroll
  for (int i = 0; i < 4; ++i) {
    int d = ty + i * 8;
    tile[d][tx] = __builtin_nontemporal_load(&src[(size_t)(d0 + d) * D_ + (e0 + tx)]);
  }
  __syncthreads();
#pragma unroll
  for (int i = 0; i < 4; ++i) {
    int e = ty + i * 8;
    const int eg = e0 + e;
    const int row = ((eg >> 4) << 6) + (z << 4) + (eg & 15);
    wT[(size_t)row * D_ + (d0 + tx)] = f2b(tile[tx][e]);
  }
}

// ---------------------------------------------------------------------------
// Kernel 1: QUAD-weight GEMM, 256x256, BK=32, 4-slot ring.
// R6: read-ahead-one-step (MFMA(t) consumes frags read during step t-1).
// R7: pin issue order with sched_barrier(0) between {stage + ds_reads(t+1)}
// and the MFMA(t) cluster. Without it the scheduler sinks the ds_reads below
// the MFMAs (shorter live ranges) -> DS pipe (1150cyc) and MFMA pipe (1242cyc)
// run serially = measured 2625 cyc/step. Pinned: reads drain under the MFMA
// cluster -> target ~1500-1700 cyc/step.
// ---------------------------------------------------------------------------
#define X4W_STEP(TT, AC, BC, AN, BN2)                                          \
  {                                                                            \
    const int tt_ = (TT);                                                      \
    if (tt_ < 30) { asm volatile("s_waitcnt vmcnt(4)" ::: "memory"); }         \
    else if (tt_ == 30) { asm volatile("s_waitcnt vmcnt(0)" ::: "memory"); }   \
    if (tt_ < 31) __builtin_amdgcn_s_barrier();                                \
    if (tt_ <= 28) {                                                           \
      short* dS = ring + ((tt_ + 3) & 3) * 16384;                              \
      const int k0_ = (tt_ + 3) * 32;                                          \
      _Pragma("unroll")                                                        \
      for (int r_ = 0; r_ < 2; ++r_) gll16(Xb + goffA[r_] + k0_, dS + ldsu[r_]); \
      _Pragma("unroll")                                                        \
      for (int r_ = 0; r_ < 2; ++r_) gll16(Wint + goffB[r_] + k0_, dS + 8192 + ldsu[r_]); \
    }                                                                          \
    if (tt_ < 31) {                                                            \
      const short* Asn = ring + ((tt_ + 1) & 3) * 16384;                       \
      const short* Bsn = Asn + 8192;                                           \
      _Pragma("unroll")                                                        \
      for (int i_ = 0; i_ < 8; ++i_) AN[i_] = *(const short8*)&Asn[aoff[i_]];  \
      _Pragma("unroll")                                                        \
      for (int j_ = 0; j_ < 4; ++j_) BN2[j_] = *(const short8*)&Bsn[boff[j_]]; \
    }                                                                          \
    __builtin_amdgcn_sched_barrier(0); /* pin: reads issued BEFORE MFMAs */    \
    __builtin_amdgcn_s_setprio(1);                                             \
    _Pragma("unroll")                                                          \
    for (int i_ = 0; i_ < 8; ++i_)                                             \
      _Pragma("unroll")                                                        \
      for (int j_ = 0; j_ < 4; ++j_)                                           \
        acc[i_][j_] = MFMA16(AC[i_], BC[j_], acc[i_][j_]);                     \
    __builtin_amdgcn_s_setprio(0);                                             \
  }

__global__ __launch_bounds__(512, 2) void gemm_x4w(
    const short* __restrict__ Xb, const short* __restrict__ Wint,
    short* __restrict__ qout, short* __restrict__ kT, short* __restrict__ vT,
    float* __restrict__ ssk, float* __restrict__ ssv) {
  __shared__ short ring[4 * 16384];  // 128 KB; epilogue reuses front as 64x264

  const int t = threadIdx.x;
  const int w = t >> 6;
  const int lane = t & 63;
  const int l16 = lane & 15;
  const int quad = lane >> 4;
  const int wm = w >> 2;
  const int wn = w & 3;

  // XCD-aware bijective swizzle (2048 blocks % 8 == 0)
  const int bid = blockIdx.x;
  const int lin = (bid & 7) * 256 + (bid >> 3);
  const int mt = lin >> 4;
  const int nt = lin & 15;
  const int M0 = mt * 256;
  const int N0 = nt * 256;
  const int E0 = nt * 64;

  const float4_t fz = {0.f, 0.f, 0.f, 0.f};
  float4_t acc[8][4];
#pragma unroll
  for (int i = 0; i < 8; ++i)
#pragma unroll
    for (int j2 = 0; j2 < 4; ++j2) acc[i][j2] = fz;

  size_t goffA[2], goffB[2];
  int ldsu[2];
#pragma unroll
  for (int r = 0; r < 2; ++r) {
    const int uu = w * 2 + r;
    const int row = uu * 16 + (lane >> 2);
    const int sp = (lane & 3) ^ ((row >> 1) & 3);
    goffA[r] = (size_t)(M0 + row) * 1024 + sp * 8;
    goffB[r] = (size_t)(N0 + row) * 1024 + sp * 8;
    ldsu[r] = uu * 512;
  }
  int aoff[8], boff[4];
#pragma unroll
  for (int i = 0; i < 8; ++i) {
    const int row = wm * 128 + i * 16 + l16;
    aoff[i] = row * 32 + ((quad ^ ((row >> 1) & 3)) << 3);
  }
#pragma unroll
  for (int j2 = 0; j2 < 4; ++j2) {
    const int row = wn * 64 + j2 * 16 + l16;
    boff[j2] = row * 32 + ((quad ^ ((row >> 1) & 3)) << 3);
  }

  // prologue: stage slots 0,1,2 (12 gll/lane in flight)
#pragma unroll
  for (int s = 0; s < 3; ++s) {
#pragma unroll
    for (int r = 0; r < 2; ++r) gll16(Xb + goffA[r] + s * 32, ring + s * 16384 + ldsu[r]);
#pragma unroll
    for (int r = 0; r < 2; ++r) gll16(Wint + goffB[r] + s * 32, ring + s * 16384 + 8192 + ldsu[r]);
  }
  asm volatile("s_waitcnt vmcnt(4)" ::: "memory");  // slots 0,1 landed; 2 may fly
  __builtin_amdgcn_s_barrier();

  short8 aFA[8], bFA[4], aFB[8], bFB[4];
  // reads(0) into buffer A
#pragma unroll
  for (int i = 0; i < 8; ++i) aFA[i] = *(const short8*)&ring[aoff[i]];
#pragma unroll
  for (int j2 = 0; j2 < 4; ++j2) bFA[j2] = *(const short8*)&ring[8192 + boff[j2]];

#pragma unroll 1
  for (int tt = 0; tt < 32; tt += 2) {
    X4W_STEP(tt, aFA, bFA, aFB, bFB);      // MFMA on A, load B
    X4W_STEP(tt + 1, aFB, bFB, aFA, bFA);  // MFMA on B, load A
  }

  // epilogue 1: query = relu*relu -> bf16 [bn][e]
  const int e = E0 + wn * 16 + l16;
#pragma unroll
  for (int i = 0; i < 8; ++i) {
    const int rowg = M0 + wm * 128 + i * 16 + quad * 4;
#pragma unroll
    for (int rr = 0; rr < 4; ++rr) {
      float v = fmaxf(acc[i][0][rr], 0.f) * fmaxf(acc[i][1][rr], 0.f);
      qout[(size_t)(rowg + rr) * 1024 + e] = f2b(v);
    }
  }

  // epilogue 2: k,v transposed -> [b][e][n] + sumsq
  short* T = ring;
  const int b = M0 >> 12;
  const int n0 = M0 & 4095;
#pragma unroll
  for (int wt = 2; wt < 4; ++wt) {
    short* dst = (wt == 2) ? kT : vT;
    float* ss = (wt == 2) ? ssk : ssv;
    __syncthreads();
#pragma unroll
    for (int i = 0; i < 8; ++i) {
      const int nl = wm * 128 + i * 16 + quad * 4;
      const int el = wn * 16 + l16;
      short4_t pk;
#pragma unroll
      for (int rr = 0; rr < 4; ++rr) pk[rr] = f2b(acc[i][wt][rr]);
      *(short4_t*)&T[el * 264 + nl] = pk;
    }
    __syncthreads();
#pragma unroll
    for (int it = 0; it < 4; ++it) {
      const int ee = it * 16 + (t >> 5);
      const int nch = (t & 31) * 8;
      short8 vv = *(const short8*)&T[ee * 264 + nch];
      *(short8*)&dst[((size_t)b * 1024 + E0 + ee) * 4096 + n0 + nch] = vv;
      float s = 0.f;
#pragma unroll
      for (int x2 = 0; x2 < 8; ++x2) { float f = b2f(vv[x2]); s += f * f; }
      s += __shfl_xor(s, 1, 32);
      s += __shfl_xor(s, 2, 32);
      s += __shfl_xor(s, 4, 32);
      s += __shfl_xor(s, 8, 32);
      s += __shfl_xor(s, 16, 32);
      if ((t & 31) == 0) atomicAdd(&ss[b * 1024 + E0 + ee], s);
    }
  }
}

// ---------------------------------------------------------------------------
// Kernel 2: inv norms
// ---------------------------------------------------------------------------
__global__ void finish_norms(const float* __restrict__ ss, float* __restrict__ inv) {
  const int i = blockIdx.x * 256 + threadIdx.x;
  if (i < 2 * BATCH_ * D_) inv[i] = 1.f / (sqrtf(ss[i]) + 1e-5f);
}

// ---------------------------------------------------------------------------
// Kernel 3: phased batched gemm_bt_p (128m x 256n, BK=32, 4-slot ring 96KB).
// R6: read-ahead-one-step; R7: sched_barrier(0) pin (see gemm_x4w).
// mode 0: out bf16 = relu(C * rs[m] * cs[n]);  mode 1: out fp32 NT.
// ---------------------------------------------------------------------------
#define BTP_STEP(TT, AC, BC, AN, BN2)                                          \
  {                                                                            \
    const int tt_ = (TT);                                                      \
    if (tt_ < NT - 2) { asm volatile("s_waitcnt vmcnt(3)" ::: "memory"); }     \
    else if (tt_ == NT - 2) { asm volatile("s_waitcnt vmcnt(0)" ::: "memory"); } \
    if (tt_ < NT - 1) __builtin_amdgcn_s_barrier();                            \
    if (tt_ <= NT - 4) {                                                       \
      short* dS = ring + ((tt_ + 3) & 3) * 12288;                              \
      const int k0_ = (tt_ + 3) * 32;                                          \
      _Pragma("unroll")                                                        \
      for (int r_ = 0; r_ < 3; ++r_) gll16(gptr[r_] + k0_, dS + ldso[r_]);     \
    }                                                                          \
    if (tt_ < NT - 1) {                                                        \
      const short* Sn = ring + ((tt_ + 1) & 3) * 12288;                        \
      _Pragma("unroll")                                                        \
      for (int i_ = 0; i_ < 4; ++i_) AN[i_] = *(const short8*)&Sn[aoff[i_]];   \
      _Pragma("unroll")                                                        \
      for (int j_ = 0; j_ < 4; ++j_) BN2[j_] = *(const short8*)&Sn[boff[j_]];  \
    }                                                                          \
    __builtin_amdgcn_sched_barrier(0); /* pin: reads issued BEFORE MFMAs */    \
    __builtin_amdgcn_s_setprio(1);                                             \
    _Pragma("unroll")                                                          \
    for (int i_ = 0; i_ < 4; ++i_)                                             \
      _Pragma("unroll")                                                        \
      for (int j_ = 0; j_ < 4; ++j_)                                           \
        acc[i_][j_] = MFMA16(AC[i_], BC[j_], acc[i_][j_]);                     \
    __builtin_amdgcn_s_setprio(0);                                             \
  }

__global__ __launch_bounds__(512, 2) void gemm_bt_p(
    const short* __restrict__ A, const short* __restrict__ Bm,
    size_t sAb, size_t sBb, int K, int mode,
    const float* __restrict__ rsb, const float* __restrict__ csb,
    void* __restrict__ outp) {
  __shared__ short ring[4 * 12288];  // 96 KB

  const int t = threadIdx.x;
  const int w = t >> 6;
  const int lane = t & 63;
  const int l16 = lane & 15;
  const int quad = lane >> 4;
  const int wm = w >> 2;
  const int wn = w & 3;
  const int M0 = blockIdx.y * 128, N0 = blockIdx.x * 256, b = blockIdx.z;
  const short* Ab = A + (size_t)b * sAb;
  const short* Bb = Bm + (size_t)b * sBb;
  const int NT = K >> 5;

  const float4_t fz = {0.f, 0.f, 0.f, 0.f};
  float4_t acc[4][4];
#pragma unroll
  for (int i = 0; i < 4; ++i)
#pragma unroll
    for (int j = 0; j < 4; ++j) acc[i][j] = fz;

  // staging units: wave w owns u = 3w..3w+2; u<8 A, u>=8 B
  const short* gptr[3];
  int ldso[3];
#pragma unroll
  for (int r = 0; r < 3; ++r) {
    const int u = w * 3 + r;
    const int lrow = (u < 8 ? u * 16 : (u - 8) * 16) + (lane >> 2);
    const int sp = (lane & 3) ^ ((lrow >> 1) & 3);
    gptr[r] = (u < 8 ? Ab + (size_t)(M0 + lrow) * K : Bb + (size_t)(N0 + lrow) * K) + sp * 8;
    ldso[r] = (u < 8 ? u * 512 : 4096 + (u - 8) * 512);
  }
  int aoff[4], boff[4];
#pragma unroll
  for (int i = 0; i < 4; ++i) {
    const int row = wm * 64 + i * 16 + l16;
    aoff[i] = row * 32 + ((quad ^ ((row >> 1) & 3)) << 3);
  }
#pragma unroll
  for (int j = 0; j < 4; ++j) {
    const int row = wn * 64 + j * 16 + l16;
    boff[j] = 4096 + row * 32 + ((quad ^ ((row >> 1) & 3)) << 3);
  }

  // prologue: stage slots 0,1,2 (9 gll/lane in flight)
#pragma unroll
  for (int s = 0; s < 3; ++s)
#pragma unroll
    for (int r = 0; r < 3; ++r) gll16(gptr[r] + s * 32, ring + s * 12288 + ldso[r]);
  asm volatile("s_waitcnt vmcnt(3)" ::: "memory");  // slots 0,1 landed
  __builtin_amdgcn_s_barrier();

  short8 aFA[4], bFA[4], aFB[4], bFB[4];
#pragma unroll
  for (int i = 0; i < 4; ++i) aFA[i] = *(const short8*)&ring[aoff[i]];
#pragma unroll
  for (int j = 0; j < 4; ++j) bFA[j] = *(const short8*)&ring[boff[j]];

#pragma unroll 1
  for (int tt = 0; tt < NT; tt += 2) {
    BTP_STEP(tt, aFA, bFA, aFB, bFB);
    BTP_STEP(tt + 1, aFB, bFB, aFA, bFA);
  }

  if (mode == 0) {
    short* ob = (short*)outp + (size_t)b * D_ * D_;
    const float* rs = rsb + b * D_ + M0;
    const float* cs = csb + b * D_ + N0;
#pragma unroll
    for (int i = 0; i < 4; ++i) {
      const int rl = wm * 64 + i * 16 + quad * 4;
#pragma unroll
      for (int j = 0; j < 4; ++j) {
        const int cl = wn * 64 + j * 16 + l16;
        const float csc = cs[cl];
#pragma unroll
        for (int rr = 0; rr < 4; ++rr) {
          float v = acc[i][j][rr] * rs[rl + rr] * csc;
          v = fmaxf(v, 0.f);
          ob[(size_t)(M0 + rl + rr) * 1024 + (N0 + cl)] = f2b(v);
        }
      }
    }
  } else {
    float* of = (float*)outp + (size_t)b * NSEQ_ * D_;
#pragma unroll
    for (int i = 0; i < 4; ++i) {
      const int rl = wm * 64 + i * 16 + quad * 4;
#pragma unroll
      for (int j = 0; j < 4; ++j) {
        const int cl = wn * 64 + j * 16 + l16;
#pragma unroll
        for (int rr = 0; rr < 4; ++rr)
          __builtin_nontemporal_store(acc[i][j][rr],
                                      &of[(size_t)(M0 + rl + rr) * 1024 + (N0 + cl)]);
      }
    }
  }
}

// ---------------------------------------------------------------------------
extern "C" void kernel_launch(void* const* d_in, const int* in_sizes, int n_in,
                              void* d_out, int out_size, void* d_ws, size_t ws_size,
                              hipStream_t stream) {
  const float* x = (const float*)d_in[0];
  const float* wqr = (const float*)d_in[1];
  const float* wqi = (const float*)d_in[2];
  const float* wk = (const float*)d_in[3];
  const float* wv = (const float*)d_in[4];

  // workspace layout (all bf16 stored as short)
  short* wT = (short*)d_ws;                          // 4 * D*D            (8 MB)
  short* qb = wT + (size_t)4 * D_ * D_;              // BN * D             (64 MB)
  short* kT = qb + (size_t)BN_ * D_;                 // B * D * N          (64 MB)
  short* vT = kT + (size_t)BATCH_ * D_ * NSEQ_;      // B * D * N          (64 MB)
  short* kvT = vT + (size_t)BATCH_ * D_ * NSEQ_;     // B * D * D          (16 MB)
  float* ssk = (float*)(kvT + (size_t)BATCH_ * D_ * D_);  // B*D
  float* ssv = ssk + BATCH_ * D_;                    // B*D
  float* invk = ssv + BATCH_ * D_;                   // B*D
  float* invv = invk + BATCH_ * D_;                  // B*D

  // bf16 x parked in d_out (only overwritten by the final GEMM, which runs
  // strictly after x's last use)
  short* xb = (short*)d_out;

  hipMemsetAsync(ssk, 0, (size_t)2 * BATCH_ * D_ * sizeof(float), stream);

  convert_x<<<dim3(16384), 256, 0, stream>>>(x, xb);

  transpose_convert_w<<<dim3(32, 32, 4), dim3(32, 8), 0, stream>>>(wqr, wqi, wk, wv, wT);

  gemm_x4w<<<dim3(2048), 512, 0, stream>>>(xb, wT, qb, kT, vT, ssk, ssv);

  finish_norms<<<dim3(64), 256, 0, stream>>>(ssk, invk);

  // kv^T[b][e][d] = relu( (sum_n V[n,e]K[n,d]) * invv[e] * invk[d] )
  gemm_bt_p<<<dim3(4, 8, 8), 512, 0, stream>>>(
      vT, kT, (size_t)D_ * NSEQ_, (size_t)D_ * NSEQ_, 4096, 0, invv, invk, (void*)kvT);

  // out[b][n][e] = sum_d query[n,d] * kv^T[e,d]   (fp32)
  gemm_bt_p<<<dim3(4, 32, 8), 512, 0, stream>>>(
      qb, kvT, (size_t)NSEQ_ * D_, (size_t)D_ * D_, 1024, 1, nullptr, nullptr, d_out);
}